// Round 2
// baseline (3074.963 us; speedup 1.0000x reference)
//
#include <hip/hip_runtime.h>

#define DEVINL __device__ __forceinline__

// ---- ordered-uint encoding for float atomicMax (bit-exact max semantics) ----
DEVINL unsigned fenc(float f) {
    unsigned u = __float_as_uint(f);
    return (u & 0x80000000u) ? ~u : (u | 0x80000000u);
}
DEVINL float fdec(unsigned k) {
    unsigned u = (k & 0x80000000u) ? (k ^ 0x80000000u) : ~k;
    return __uint_as_float(u);
}

// ---- async global->LDS copy, 4 bytes per lane ----
DEVINL void gload_lds4(const float* g, float* l) {
    __builtin_amdgcn_global_load_lds(
        (const __attribute__((address_space(1))) unsigned int*)(const void*)g,
        (__attribute__((address_space(3))) unsigned int*)(void*)l,
        4, 0, 0);
}

// ---- zero init (ws is poisoned 0xAA before every call) ----
__global__ void zero_kernel(float* __restrict__ p, long n) {
    long i = (long)blockIdx.x * blockDim.x + threadIdx.x;
    long stride = (long)gridDim.x * blockDim.x;
    for (; i < n; i += stride) p[i] = 0.f;
}

// ---- pack W_pad[385][128] = [We1 | We2 | We3 | 0] ----
__global__ __launch_bounds__(256) void pack_w(
    const float* __restrict__ We1, const float* __restrict__ We2,
    const float* __restrict__ We3, float* __restrict__ Wp)
{
    int idx = blockIdx.x * 256 + threadIdx.x;
    if (idx >= 385 * 128) return;
    int k = idx >> 7, c = idx & 127;
    float v = 0.f;
    if (c < 64)       v = We1[k * 64 + c];
    else if (c < 96)  v = We2[k * 32 + (c - 64)];
    else if (c < 112) v = We3[k * 16 + (c - 96)];
    Wp[idx] = v;
}

// ---- node transform: xl = act(x)@Wl + bl, xr = act(x)@Wr + br
//      PRE=1: x is a raw accumulator -> apply (x + pre_bias) then ELU on the fly ----
template<int IN, int HC, int PRE>
__global__ __launch_bounds__(256) void node_transform(
    const float* __restrict__ x, const int* __restrict__ gather,
    const float* __restrict__ pre_bias,
    const float* __restrict__ Wl, const float* __restrict__ bl,
    const float* __restrict__ Wr, const float* __restrict__ br,
    float* __restrict__ xl, float* __restrict__ xr, int N)
{
    __shared__ float Wls[IN * HC];
    __shared__ float Wrs[IN * HC];
    __shared__ float pbs[IN];
    for (int i = threadIdx.x; i < IN * HC; i += 256) { Wls[i] = Wl[i]; Wrs[i] = Wr[i]; }
    if (PRE && threadIdx.x < IN) pbs[threadIdx.x] = pre_bias[threadIdx.x];
    __syncthreads();
    constexpr int NPB = 256 / HC;
    const int c = threadIdx.x % HC;
    const int n = blockIdx.x * NPB + threadIdx.x / HC;
    if (n >= N) return;
    const int row = gather ? gather[n] : n;
    const float* xp = x + (long)row * IN;
    float al = bl[c], ar = br[c];
#pragma unroll
    for (int k = 0; k < IN; ++k) {
        float v = xp[k];
        if (PRE) { v += pbs[k]; v = (v > 0.f) ? v : expm1f(v); }
        al = fmaf(v, Wls[k * HC + c], al);
        ar = fmaf(v, Wrs[k * HC + c], ar);
    }
    xl[(long)n * HC + c] = al;
    xr[(long)n * HC + c] = ar;
}

// ---- fused edge projection for ALL layers + layer-1 logits ----
// EA[E][128] = eattr @ Wpad (K chunked by 32, k=384 peeled).
// cols 0-63  -> layer-1 logits (leaky + att-dot + atomicMax), never stored
// cols 64-95 -> ea2,  cols 96-111 -> ea3,  cols 112-127 -> discarded pad.
// Double-buffered LDS staging with counted vmcnt(32) across raw s_barriers.
__global__ __launch_bounds__(256) void ea_gat1(
    const float* __restrict__ eattr, const float* __restrict__ Wpad,
    const float* __restrict__ xl, const float* __restrict__ xr,
    const float* __restrict__ att, const int* __restrict__ src,
    const int* __restrict__ dst,
    float* __restrict__ lg1, unsigned* __restrict__ mkey,
    float* __restrict__ ea2, float* __restrict__ ea3, int E)
{
    constexpr int KC = 32, NKM = 12, COLS = 128, TILE_E = 128;
    __shared__ float As[2][TILE_E * KC];   // 2 x 16 KB, source-swizzled
    __shared__ float Bs[2][KC * COLS];     // 2 x 16 KB, linear

    const int tid = threadIdx.x;
    const int tx = tid & 15, ty = tid >> 4;    // TX=16 (OPT=8), TY=16 (EPT=8)
    const long eblk = (long)blockIdx.x * TILE_E;

    float acc[8][8];
#pragma unroll
    for (int i = 0; i < 8; ++i)
#pragma unroll
        for (int j = 0; j < 8; ++j) acc[i][j] = 0.f;

    auto issue = [&](int buf, int kc) {
        const int k0 = kc * KC;
        // A tile: 128x32, source pre-swizzled so linear LDS + swizzled read are conflict-free
#pragma unroll
        for (int i = 0; i < 16; ++i) {
            const int idx = tid + i * 256;
            const int row = idx >> 5, c = idx & 31;
            const int klog = (((c >> 2) ^ ((row >> 2) & 7)) << 2) | (c & 3);
            long ge = eblk + row;
            ge = (ge < E) ? ge : (long)(E - 1);   // clamp; discarded in epilogue
            gload_lds4(eattr + ge * 385 + (k0 + klog), &As[buf][idx]);
        }
        // B tile: 32x128 linear
#pragma unroll
        for (int i = 0; i < 16; ++i) {
            const int idx = tid + i * 256;
            gload_lds4(Wpad + (long)k0 * COLS + idx, &Bs[buf][idx]);
        }
    };

    issue(0, 0);
    int cur = 0;
#pragma unroll 1
    for (int kc = 0; kc < NKM; ++kc) {
        if (kc + 1 < NKM) {
            issue(cur ^ 1, kc + 1);                          // 32 new loads in flight
            asm volatile("s_waitcnt vmcnt(32)" ::: "memory"); // chunk kc's 32 retired
        } else {
            asm volatile("s_waitcnt vmcnt(0)" ::: "memory");
        }
        __builtin_amdgcn_s_barrier();
        const float* Ab = As[cur];
        const float* Bb = Bs[cur];
#pragma unroll
        for (int g = 0; g < 8; ++g) {
            float a[8][4];
#pragma unroll
            for (int i = 0; i < 8; ++i) {
                const int row = ty * 8 + i;
                const float4 v = *(const float4*)&Ab[row * KC + ((g ^ ((row >> 2) & 7)) << 2)];
                a[i][0] = v.x; a[i][1] = v.y; a[i][2] = v.z; a[i][3] = v.w;
            }
#pragma unroll
            for (int q = 0; q < 4; ++q) {
                float b[8];
#pragma unroll
                for (int j = 0; j < 8; j += 4) {
                    const float4 bv = *(const float4*)&Bb[(g * 4 + q) * COLS + tx * 8 + j];
                    b[j] = bv.x; b[j + 1] = bv.y; b[j + 2] = bv.z; b[j + 3] = bv.w;
                }
#pragma unroll
                for (int i = 0; i < 8; ++i)
#pragma unroll
                    for (int j = 0; j < 8; ++j)
                        acc[i][j] = fmaf(a[i][q], b[j], acc[i][j]);
            }
        }
        __builtin_amdgcn_s_barrier();   // all waves done with buf (cur) before overwrite
        cur ^= 1;
    }

    // part[] aliases As (GEMM done with LDS; last barrier above protects reuse)
    float (*part)[9] = reinterpret_cast<float(*)[9]>(&As[0][0]);

    const int col0 = tx * 8;
    float w384[8];
#pragma unroll
    for (int j = 0; j < 8; ++j) w384[j] = Wpad[384 * 128 + col0 + j];

    if (col0 < 64) {
        // ---- layer-1 logit partials ----
        const int h = col0 >> 4, cb = col0 & 15;
        float av[8];
#pragma unroll
        for (int j = 0; j < 8; ++j) av[j] = att[h * 16 + cb + j];
#pragma unroll
        for (int i = 0; i < 8; ++i) {
            const int el = ty * 8 + i;
            const long ge = eblk + el;
            float p = 0.f;
            if (ge < E) {
                const float a384 = eattr[ge * 385 + 384];
                const float* xlp = xl + (long)src[ge] * 64 + col0;
                const float* xrp = xr + (long)dst[ge] * 64 + col0;
#pragma unroll
                for (int j = 0; j < 8; j += 4) {
                    const float4 vj = *(const float4*)(xlp + j);
                    const float4 vi = *(const float4*)(xrp + j);
                    float t0 = fmaf(a384, w384[j + 0], acc[i][j + 0]) + vj.x + vi.x;
                    float t1 = fmaf(a384, w384[j + 1], acc[i][j + 1]) + vj.y + vi.y;
                    float t2 = fmaf(a384, w384[j + 2], acc[i][j + 2]) + vj.z + vi.z;
                    float t3 = fmaf(a384, w384[j + 3], acc[i][j + 3]) + vj.w + vi.w;
                    t0 = (t0 > 0.f) ? t0 : 0.2f * t0;
                    t1 = (t1 > 0.f) ? t1 : 0.2f * t1;
                    t2 = (t2 > 0.f) ? t2 : 0.2f * t2;
                    t3 = (t3 > 0.f) ? t3 : 0.2f * t3;
                    p = fmaf(t0, av[j + 0], p);
                    p = fmaf(t1, av[j + 1], p);
                    p = fmaf(t2, av[j + 2], p);
                    p = fmaf(t3, av[j + 3], p);
                }
            }
            part[el][tx] = p;
        }
    } else if (col0 < 96) {
        // ---- ea2 store ----
        const int c2 = col0 - 64;
#pragma unroll
        for (int i = 0; i < 8; ++i) {
            const long ge = eblk + ty * 8 + i;
            if (ge < E) {
                const float a384 = eattr[ge * 385 + 384];
                float4 o0, o1;
                o0.x = fmaf(a384, w384[0], acc[i][0]);
                o0.y = fmaf(a384, w384[1], acc[i][1]);
                o0.z = fmaf(a384, w384[2], acc[i][2]);
                o0.w = fmaf(a384, w384[3], acc[i][3]);
                o1.x = fmaf(a384, w384[4], acc[i][4]);
                o1.y = fmaf(a384, w384[5], acc[i][5]);
                o1.z = fmaf(a384, w384[6], acc[i][6]);
                o1.w = fmaf(a384, w384[7], acc[i][7]);
                *(float4*)&ea2[ge * 32 + c2]     = o0;
                *(float4*)&ea2[ge * 32 + c2 + 4] = o1;
            }
        }
    } else if (col0 < 112) {
        // ---- ea3 store ----
        const int c3 = col0 - 96;
#pragma unroll
        for (int i = 0; i < 8; ++i) {
            const long ge = eblk + ty * 8 + i;
            if (ge < E) {
                const float a384 = eattr[ge * 385 + 384];
                float4 o0, o1;
                o0.x = fmaf(a384, w384[0], acc[i][0]);
                o0.y = fmaf(a384, w384[1], acc[i][1]);
                o0.z = fmaf(a384, w384[2], acc[i][2]);
                o0.w = fmaf(a384, w384[3], acc[i][3]);
                o1.x = fmaf(a384, w384[4], acc[i][4]);
                o1.y = fmaf(a384, w384[5], acc[i][5]);
                o1.z = fmaf(a384, w384[6], acc[i][6]);
                o1.w = fmaf(a384, w384[7], acc[i][7]);
                *(float4*)&ea3[ge * 16 + c3]     = o0;
                *(float4*)&ea3[ge * 16 + c3 + 4] = o1;
            }
        }
    }
    __syncthreads();

    // layer-1 logit reduce (2 partials per head) + atomicMax
    for (int idx = tid; idx < TILE_E * 4; idx += 256) {
        const int e = idx >> 2, hh = idx & 3;
        const long ge = eblk + e;
        if (ge < E) {
            const float l = part[e][hh * 2] + part[e][hh * 2 + 1];
            lg1[ge * 4 + hh] = l;
            atomicMax(&mkey[(unsigned)dst[ge] * 4 + hh], fenc(l));
        }
    }
}

// ---- per-edge logits for layers 2/3: one thread per (edge, head) ----
template<int H, int HC>
__global__ __launch_bounds__(256) void edge_logits(
    const float* __restrict__ ea, const float* __restrict__ xl,
    const float* __restrict__ xr, const float* __restrict__ att,
    const int* __restrict__ src, const int* __restrict__ dst,
    float* __restrict__ lg, unsigned* __restrict__ mkey, int E)
{
    int idx = blockIdx.x * 256 + threadIdx.x;
    if (idx >= E * H) return;
    const int e = idx / H, h = idx % H;
    const int s = src[e], d = dst[e];
    const float* eap = ea + (long)e * HC + h * 16;
    const float* xlp = xl + (long)s * HC + h * 16;
    const float* xrp = xr + (long)d * HC + h * 16;
    float p = 0.f;
#pragma unroll
    for (int j = 0; j < 16; j += 4) {
        const float4 ev = *(const float4*)(eap + j);
        const float4 vj = *(const float4*)(xlp + j);
        const float4 vi = *(const float4*)(xrp + j);
        const float4 av = *(const float4*)(att + h * 16 + j);
        float t0 = ev.x + vj.x + vi.x;
        float t1 = ev.y + vj.y + vi.y;
        float t2 = ev.z + vj.z + vi.z;
        float t3 = ev.w + vj.w + vi.w;
        t0 = (t0 > 0.f) ? t0 : 0.2f * t0;
        t1 = (t1 > 0.f) ? t1 : 0.2f * t1;
        t2 = (t2 > 0.f) ? t2 : 0.2f * t2;
        t3 = (t3 > 0.f) ? t3 : 0.2f * t3;
        p = fmaf(t0, av.x, p);
        p = fmaf(t1, av.y, p);
        p = fmaf(t2, av.z, p);
        p = fmaf(t3, av.w, p);
    }
    lg[idx] = p;
    atomicMax(&mkey[(unsigned)d * H + h], fenc(p));
}

// ---- softmax pass B: ex = exp(logit - max); atomic sum per dst; in-place store ----
template<int H>
__global__ __launch_bounds__(256) void softmax_ex(
    float* __restrict__ lg, const unsigned* __restrict__ mkey,
    float* __restrict__ ssum, const int* __restrict__ dst, int E)
{
    int idx = blockIdx.x * 256 + threadIdx.x;
    if (idx >= E * H) return;
    int e = idx / H, h = idx % H;
    int d = dst[e];
    float m = fdec(mkey[d * H + h]);
    float ex = expf(lg[idx] - m);
    lg[idx] = ex;
    atomicAdd(&ssum[d * H + h], ex);
}

// ---- pass C: acc[dst] += xl[src] * alpha  (4 channels per thread) ----
template<int HC>
__global__ __launch_bounds__(256) void aggregate(
    const float* __restrict__ ex, const float* __restrict__ ssum,
    const float* __restrict__ xl, const int* __restrict__ src,
    const int* __restrict__ dst, float* __restrict__ acc, int E)
{
    constexpr int H = HC / 16;
    constexpr int C4 = HC / 4;
    long idx = (long)blockIdx.x * 256 + threadIdx.x;
    if (idx >= (long)E * C4) return;
    const int e = (int)(idx / C4), c4 = (int)(idx % C4);
    const int c = c4 * 4, h = c >> 4;
    const int d = dst[e], s = src[e];
    const float alpha = ex[(long)e * H + h] / (ssum[d * H + h] + 1e-16f);
    const float4 v = *(const float4*)&xl[(long)s * HC + c];
    float* ap = &acc[(long)d * HC + c];
    atomicAdd(ap + 0, v.x * alpha);
    atomicAdd(ap + 1, v.y * alpha);
    atomicAdd(ap + 2, v.z * alpha);
    atomicAdd(ap + 3, v.w * alpha);
}

// ---- finalize: x = (acc + bias), optional ELU ----
__global__ __launch_bounds__(256) void finalize_k(
    const float* __restrict__ acc, const float* __restrict__ bias,
    float* __restrict__ xout, int total, int HC, int do_elu)
{
    int idx = blockIdx.x * 256 + threadIdx.x;
    if (idx >= total) return;
    float v = acc[idx] + bias[idx % HC];
    if (do_elu) v = (v > 0.f) ? v : expm1f(v);
    xout[idx] = v;
}

// ---- edge MLP: out[e] = W3 @ relu(W2 @ relu(W1 @ [x3[src], x3[dst]] + b1) + b2) + b3 ----
__global__ __launch_bounds__(256) void edge_mlp(
    const float* __restrict__ x3, const int* __restrict__ src, const int* __restrict__ dst,
    const float* __restrict__ W1, const float* __restrict__ b1,
    const float* __restrict__ W2, const float* __restrict__ b2,
    const float* __restrict__ W3, const float* __restrict__ b3,
    float* __restrict__ out, int E)
{
    int e = blockIdx.x * 256 + threadIdx.x;
    if (e >= E) return;
    float in[32];
    const float* xs = x3 + (long)src[e] * 16;
    const float* xd = x3 + (long)dst[e] * 16;
#pragma unroll
    for (int k = 0; k < 16; k += 4) {
        float4 a = *(const float4*)(xs + k);
        float4 b = *(const float4*)(xd + k);
        in[k] = a.x; in[k + 1] = a.y; in[k + 2] = a.z; in[k + 3] = a.w;
        in[16 + k] = b.x; in[16 + k + 1] = b.y; in[16 + k + 2] = b.z; in[16 + k + 3] = b.w;
    }
    float h1[64];
#pragma unroll
    for (int j = 0; j < 64; ++j) h1[j] = b1[j];
#pragma unroll
    for (int k = 0; k < 32; ++k) {
        float a = in[k];
#pragma unroll
        for (int j = 0; j < 64; ++j) h1[j] = fmaf(a, W1[k * 64 + j], h1[j]);
    }
    float h2[32];
#pragma unroll
    for (int j = 0; j < 32; ++j) h2[j] = b2[j];
#pragma unroll
    for (int k = 0; k < 64; ++k) {
        float a = h1[k] > 0.f ? h1[k] : 0.f;
#pragma unroll
        for (int j = 0; j < 32; ++j) h2[j] = fmaf(a, W2[k * 32 + j], h2[j]);
    }
    float o = b3[0];
#pragma unroll
    for (int j = 0; j < 32; ++j) {
        float a = h2[j] > 0.f ? h2[j] : 0.f;
        o = fmaf(a, W3[j], o);
    }
    out[e] = o;
}

extern "C" void kernel_launch(void* const* d_in, const int* in_sizes, int n_in,
                              void* d_out, int out_size, void* d_ws, size_t ws_size,
                              hipStream_t stream) {
    const int N = in_sizes[0];
    const int E = in_sizes[1] / 2;

    const int*   node_ids = (const int*)d_in[0];
    const int*   src      = (const int*)d_in[1];
    const int*   dst      = src + E;
    const float* eattr    = (const float*)d_in[2];
    const float* node_emb = (const float*)d_in[3];
    const float* l1_Wl = (const float*)d_in[4],  *l1_bl = (const float*)d_in[5];
    const float* l1_Wr = (const float*)d_in[6],  *l1_br = (const float*)d_in[7];
    const float* l1_We = (const float*)d_in[8],  *l1_att = (const float*)d_in[9];
    const float* l1_bias = (const float*)d_in[10];
    const float* l2_Wl = (const float*)d_in[11], *l2_bl = (const float*)d_in[12];
    const float* l2_Wr = (const float*)d_in[13], *l2_br = (const float*)d_in[14];
    const float* l2_We = (const float*)d_in[15], *l2_att = (const float*)d_in[16];
    const float* l2_bias = (const float*)d_in[17];
    const float* l3_Wl = (const float*)d_in[18], *l3_bl = (const float*)d_in[19];
    const float* l3_Wr = (const float*)d_in[20], *l3_br = (const float*)d_in[21];
    const float* l3_We = (const float*)d_in[22], *l3_att = (const float*)d_in[23];
    const float* l3_bias = (const float*)d_in[24];
    const float* mW1 = (const float*)d_in[25], *mb1 = (const float*)d_in[26];
    const float* mW2 = (const float*)d_in[27], *mb2 = (const float*)d_in[28];
    const float* mW3 = (const float*)d_in[29], *mb3 = (const float*)d_in[30];
    float* out = (float*)d_out;

    // ---- workspace layout (floats), 256B-aligned slices ----
    float* base = (float*)d_ws;
    size_t o = 0;
    auto alloc = [&](size_t n) { float* p = base + o; o += (n + 63) & ~(size_t)63; return p; };
    float* acc1  = alloc((size_t)N * 64);
    float* acc2  = alloc((size_t)N * 32);
    float* acc3  = alloc((size_t)N * 16);
    float* ssum1 = alloc((size_t)N * 4);
    float* ssum2 = alloc((size_t)N * 2);
    float* ssum3 = alloc((size_t)N);
    unsigned* mkey1 = (unsigned*)alloc((size_t)N * 4);
    unsigned* mkey2 = (unsigned*)alloc((size_t)N * 2);
    unsigned* mkey3 = (unsigned*)alloc((size_t)N);
    const size_t zero_end = o;           // everything above must start at 0
    float* xl  = alloc((size_t)N * 64);
    float* xr  = alloc((size_t)N * 64);
    float* x3  = alloc((size_t)N * 16);
    float* ea2 = alloc((size_t)E * 32);
    float* ea3 = alloc((size_t)E * 16);
    float* lg1 = alloc((size_t)E * 4);
    float* lg2 = alloc((size_t)E * 2);
    float* lg3 = alloc((size_t)E);
    float* Wpad = alloc((size_t)385 * 128);
    (void)ws_size; (void)n_in; (void)out_size;

    zero_kernel<<<1024, 256, 0, stream>>>(base, (long)zero_end);
    pack_w<<<(385 * 128 + 255) / 256, 256, 0, stream>>>(l1_We, l2_We, l3_We, Wpad);

    // ---- layer 1 node transform ----
    node_transform<32, 64, 0><<<(N + 3) / 4, 256, 0, stream>>>(
        node_emb, node_ids, nullptr, l1_Wl, l1_bl, l1_Wr, l1_br, xl, xr, N);

    // ---- fused edge projection (all layers) + layer-1 logits ----
    ea_gat1<<<(E + 127) / 128, 256, 0, stream>>>(
        eattr, Wpad, xl, xr, l1_att, src, dst, lg1, mkey1, ea2, ea3, E);
    softmax_ex<4><<<(E * 4 + 255) / 256, 256, 0, stream>>>(lg1, mkey1, ssum1, dst, E);
    aggregate<64><<<(int)(((long)E * 16 + 255) / 256), 256, 0, stream>>>(
        lg1, ssum1, xl, src, dst, acc1, E);

    // ---- layer 2 (bias+ELU of layer-1 fused into transform) ----
    node_transform<64, 32, 1><<<(N + 7) / 8, 256, 0, stream>>>(
        acc1, nullptr, l1_bias, l2_Wl, l2_bl, l2_Wr, l2_br, xl, xr, N);
    edge_logits<2, 32><<<(E * 2 + 255) / 256, 256, 0, stream>>>(
        ea2, xl, xr, l2_att, src, dst, lg2, mkey2, E);
    softmax_ex<2><<<(E * 2 + 255) / 256, 256, 0, stream>>>(lg2, mkey2, ssum2, dst, E);
    aggregate<32><<<(int)(((long)E * 8 + 255) / 256), 256, 0, stream>>>(
        lg2, ssum2, xl, src, dst, acc2, E);

    // ---- layer 3 ----
    node_transform<32, 16, 1><<<(N + 15) / 16, 256, 0, stream>>>(
        acc2, nullptr, l2_bias, l3_Wl, l3_bl, l3_Wr, l3_br, xl, xr, N);
    edge_logits<1, 16><<<(E + 255) / 256, 256, 0, stream>>>(
        ea3, xl, xr, l3_att, src, dst, lg3, mkey3, E);
    softmax_ex<1><<<(E + 255) / 256, 256, 0, stream>>>(lg3, mkey3, ssum3, dst, E);
    aggregate<16><<<(int)(((long)E * 4 + 255) / 256), 256, 0, stream>>>(
        lg3, ssum3, xl, src, dst, acc3, E);
    finalize_k<<<(N * 16 + 255) / 256, 256, 0, stream>>>(acc3, l3_bias, x3, N * 16, 16, 0);

    // ---- edge MLP ----
    edge_mlp<<<(E + 255) / 256, 256, 0, stream>>>(
        x3, src, dst, mW1, mb1, mW2, mb2, mW3, mb3, out, E);
}